// Round 4
// baseline (250.439 us; speedup 1.0000x reference)
//
#include <hip/hip_runtime.h>

#define TPB  256
#define MPB  512            // matrices per block (2 per thread)
#define F4PB 1152           // float4 chunks per block = MPB*9/4

// Jacobi pivot in plane (p,q). 2 transcendentals (sqrt, rsq), no rcp.
// d' = sign(d)*sqrt(d^2+4apq^2) gives post-rotation diagonal directly:
//   app' = (app+aqq - d')/2, aqq' = (app+aqq + d')/2   (sign(apq)-independent).
// c = h*inv, s = sign(d)*p2*inv, h = |d|+rad, inv = rsq(h^2+p2^2), p2 = 2apq.
// NOTE: s must KEEP p2's sign as a factor: s = p2*copysign(inv,d).
// (copysignf(p2*inv, d) was the round-3 bug: it discarded sign(p2).)
// +1e-18 bias on h: all-zero plane degenerates to identity (c=1,s=0),
// and h^2 = 1e-36 > FLT_MIN so FTZ can't zero it.
__device__ __forceinline__ void pivot(float& app, float& aqq, float& apq,
                                      float& arp, float& arq,
                                      float& vp0, float& vq0,
                                      float& vp1, float& vq1,
                                      float& vp2, float& vq2)
{
    float d   = aqq - app;
    float p2  = apq + apq;
    float rad = __builtin_amdgcn_sqrtf(fmaf(d, d, p2 * p2));
    float h   = fabsf(d) + rad + 1e-18f;
    float inv = __builtin_amdgcn_rsqf(fmaf(h, h, p2 * p2));
    float c   = h * inv;
    float s   = p2 * copysignf(inv, d);     // sign(d)*p2*inv  (inv > 0)
    float sum = app + aqq;
    float sr  = copysignf(rad, d);
    app = 0.5f * (sum - sr);
    aqq = 0.5f * (sum + sr);
    apq = 0.f;
    float x;
    x = fmaf(c, arp, -s * arq); arq = fmaf(s, arp, c * arq); arp = x;
    x = fmaf(c, vp0, -s * vq0); vq0 = fmaf(s, vp0, c * vq0); vp0 = x;
    x = fmaf(c, vp1, -s * vq1); vq1 = fmaf(s, vp1, c * vq1); vp1 = x;
    x = fmaf(c, vp2, -s * vq2); vq2 = fmaf(s, vp2, c * vq2); vp2 = x;
}

// Sort eigenpairs, build U columns, emit R = U~ V~^T. v is row-major v[r*3+c].
__device__ __forceinline__ void finish(const float F[9],
                                       float l0, float l1, float l2,
                                       float v[9], float Rm[9])
{
    float t;
    if (l0 < l1) { t=l0;l0=l1;l1=t; t=v[0];v[0]=v[1];v[1]=t;
                   t=v[3];v[3]=v[4];v[4]=t; t=v[6];v[6]=v[7];v[7]=t; }
    if (l0 < l2) { t=l0;l0=l2;l2=t; t=v[0];v[0]=v[2];v[2]=t;
                   t=v[3];v[3]=v[5];v[5]=t; t=v[6];v[6]=v[8];v[8]=t; }
    if (l1 < l2) { t=l1;l1=l2;l2=t; t=v[1];v[1]=v[2];v[2]=t;
                   t=v[4];v[4]=v[5];v[5]=t; t=v[7];v[7]=v[8];v[8]=t; }

    // v3 = v1 x v2 (right-handed, unit)
    float v3x = v[3]*v[7] - v[6]*v[4];
    float v3y = v[6]*v[1] - v[0]*v[7];
    float v3z = v[0]*v[4] - v[3]*v[1];

    // u1 = normalize(F v1)
    float u1x = F[0]*v[0] + F[1]*v[3] + F[2]*v[6];
    float u1y = F[3]*v[0] + F[4]*v[3] + F[5]*v[6];
    float u1z = F[6]*v[0] + F[7]*v[3] + F[8]*v[6];
    float inv1 = __builtin_amdgcn_rsqf(fmaxf(u1x*u1x + u1y*u1y + u1z*u1z, 1e-30f));
    u1x *= inv1; u1y *= inv1; u1z *= inv1;

    // u2 = normalize(F v2 - (u1 . F v2) u1)
    float wx = F[0]*v[1] + F[1]*v[4] + F[2]*v[7];
    float wy = F[3]*v[1] + F[4]*v[4] + F[5]*v[7];
    float wz = F[6]*v[1] + F[7]*v[4] + F[8]*v[7];
    float dd = u1x*wx + u1y*wy + u1z*wz;
    wx -= dd*u1x; wy -= dd*u1y; wz -= dd*u1z;
    float inv2 = __builtin_amdgcn_rsqf(fmaxf(wx*wx + wy*wy + wz*wz, 1e-30f));
    float u2x = wx*inv2, u2y = wy*inv2, u2z = wz*inv2;

    // u3 = u1 x u2
    float u3x = u1y*u2z - u1z*u2y;
    float u3y = u1z*u2x - u1x*u2z;
    float u3z = u1x*u2y - u1y*u2x;

    Rm[0] = u1x*v[0] + u2x*v[1] + u3x*v3x;
    Rm[1] = u1x*v[3] + u2x*v[4] + u3x*v3y;
    Rm[2] = u1x*v[6] + u2x*v[7] + u3x*v3z;
    Rm[3] = u1y*v[0] + u2y*v[1] + u3y*v3x;
    Rm[4] = u1y*v[3] + u2y*v[4] + u3y*v3y;
    Rm[5] = u1y*v[6] + u2y*v[7] + u3y*v3z;
    Rm[6] = u1z*v[0] + u2z*v[1] + u3z*v3x;
    Rm[7] = u1z*v[3] + u2z*v[4] + u3z*v3y;
    Rm[8] = u1z*v[6] + u2z*v[7] + u3z*v3z;
}

__global__ __launch_bounds__(TPB)
void so3_proj_kernel(const float* __restrict__ Rc,
                     const float* __restrict__ Tt,
                     const float* __restrict__ Nz,
                     const float* __restrict__ Ez,
                     float* __restrict__ Out,
                     int L)
{
    __shared__ float4 lds4[F4PB];
    float* lds = (float*)lds4;

    const int tid = threadIdx.x;
    const long long base = (long long)blockIdx.x * MPB;
    const int n = (int)(base / (long long)L);     // uniform per block (512 | 8192)
    const float alpha = Tt[n];                    // BETA = 1
    const float sa = __builtin_amdgcn_sqrtf(alpha);

    const float4* R4 = (const float4*)(Rc + base * 9);
    const float4* N4 = (const float4*)(Nz + base * 9);
    const float4* E4 = (const float4*)(Ez + base * 9);
    float4*       O4 = (float4*)(Out + base * 9);

    // ---- stage F = alpha*R + sqrt(alpha)*noise + 1e-6*eps into LDS (vectorized)
    #pragma unroll
    for (int it = 0; it < 5; ++it) {
        int j = tid + it * TPB;
        if (j < F4PB) {
            float4 r = R4[j], z = N4[j], e = E4[j];
            float4 f;
            f.x = fmaf(alpha, r.x, fmaf(sa, z.x, 1e-6f * e.x));
            f.y = fmaf(alpha, r.y, fmaf(sa, z.y, 1e-6f * e.y));
            f.z = fmaf(alpha, r.z, fmaf(sa, z.z, 1e-6f * e.z));
            f.w = fmaf(alpha, r.w, fmaf(sa, z.w, 1e-6f * e.w));
            lds4[j] = f;
        }
    }
    __syncthreads();

    // two independent matrices per thread
    float Fa[9], Fb[9];
    #pragma unroll
    for (int k = 0; k < 9; ++k) Fa[k] = lds[tid * 9 + k];
    #pragma unroll
    for (int k = 0; k < 9; ++k) Fb[k] = lds[(tid + TPB) * 9 + k];

    // A = F^T F (6 uniques each)
    float Aa00 = Fa[0]*Fa[0] + Fa[3]*Fa[3] + Fa[6]*Fa[6];
    float Aa01 = Fa[0]*Fa[1] + Fa[3]*Fa[4] + Fa[6]*Fa[7];
    float Aa02 = Fa[0]*Fa[2] + Fa[3]*Fa[5] + Fa[6]*Fa[8];
    float Aa11 = Fa[1]*Fa[1] + Fa[4]*Fa[4] + Fa[7]*Fa[7];
    float Aa12 = Fa[1]*Fa[2] + Fa[4]*Fa[5] + Fa[7]*Fa[8];
    float Aa22 = Fa[2]*Fa[2] + Fa[5]*Fa[5] + Fa[8]*Fa[8];

    float Ab00 = Fb[0]*Fb[0] + Fb[3]*Fb[3] + Fb[6]*Fb[6];
    float Ab01 = Fb[0]*Fb[1] + Fb[3]*Fb[4] + Fb[6]*Fb[7];
    float Ab02 = Fb[0]*Fb[2] + Fb[3]*Fb[5] + Fb[6]*Fb[8];
    float Ab11 = Fb[1]*Fb[1] + Fb[4]*Fb[4] + Fb[7]*Fb[7];
    float Ab12 = Fb[1]*Fb[2] + Fb[4]*Fb[5] + Fb[7]*Fb[8];
    float Ab22 = Fb[2]*Fb[2] + Fb[5]*Fb[5] + Fb[8]*Fb[8];

    float Va[9] = {1.f,0.f,0.f, 0.f,1.f,0.f, 0.f,0.f,1.f};
    float Vb[9] = {1.f,0.f,0.f, 0.f,1.f,0.f, 0.f,0.f,1.f};

    for (int sweep = 0; sweep < 5; ++sweep) {
        if (sweep >= 3) {
            float offA = fmaf(Aa01, Aa01, fmaf(Aa02, Aa02, Aa12 * Aa12));
            float scA  = fmaf(Aa00, Aa00, fmaf(Aa11, Aa11, Aa22 * Aa22));
            float offB = fmaf(Ab01, Ab01, fmaf(Ab02, Ab02, Ab12 * Ab12));
            float scB  = fmaf(Ab00, Ab00, fmaf(Ab11, Ab11, Ab22 * Ab22));
            if (__all((offA <= 1e-13f * scA) && (offB <= 1e-13f * scB))) break;
        }
        // pivots interleaved A/B so two independent trans-chains overlap
        pivot(Aa00, Aa11, Aa01, Aa02, Aa12, Va[0],Va[1], Va[3],Va[4], Va[6],Va[7]);
        pivot(Ab00, Ab11, Ab01, Ab02, Ab12, Vb[0],Vb[1], Vb[3],Vb[4], Vb[6],Vb[7]);
        pivot(Aa00, Aa22, Aa02, Aa01, Aa12, Va[0],Va[2], Va[3],Va[5], Va[6],Va[8]);
        pivot(Ab00, Ab22, Ab02, Ab01, Ab12, Vb[0],Vb[2], Vb[3],Vb[5], Vb[6],Vb[8]);
        pivot(Aa11, Aa22, Aa12, Aa01, Aa02, Va[1],Va[2], Va[4],Va[5], Va[7],Va[8]);
        pivot(Ab11, Ab22, Ab12, Ab01, Ab02, Vb[1],Vb[2], Vb[4],Vb[5], Vb[7],Vb[8]);
    }

    float Ra[9], Rb[9];
    finish(Fa, Aa00, Aa11, Aa22, Va, Ra);
    finish(Fb, Ab00, Ab11, Ab22, Vb, Rb);

    // ---- stage results through LDS for vectorized store
    __syncthreads();
    #pragma unroll
    for (int k = 0; k < 9; ++k) lds[tid * 9 + k] = Ra[k];
    #pragma unroll
    for (int k = 0; k < 9; ++k) lds[(tid + TPB) * 9 + k] = Rb[k];
    __syncthreads();

    #pragma unroll
    for (int it = 0; it < 5; ++it) {
        int j = tid + it * TPB;
        if (j < F4PB) O4[j] = lds4[j];
    }
}

extern "C" void kernel_launch(void* const* d_in, const int* in_sizes, int n_in,
                              void* d_out, int out_size, void* d_ws, size_t ws_size,
                              hipStream_t stream) {
    const float* Rc = (const float*)d_in[0];   // R_clean (N,L,3,3)
    const float* Tt = (const float*)d_in[1];   // t (N,)
    const float* Nz = (const float*)d_in[2];   // noise
    const float* Ez = (const float*)d_in[3];   // eps_noise
    float* Out = (float*)d_out;

    const long long mats = (long long)in_sizes[0] / 9;   // 2097152
    const int L = (int)(mats / in_sizes[1]);             // 8192
    const int blocks = (int)(mats / MPB);                // 4096

    so3_proj_kernel<<<blocks, TPB, 0, stream>>>(Rc, Tt, Nz, Ez, Out, L);
}